// Round 2
// baseline (5162.531 us; speedup 1.0000x reference)
//
#include <hip/hip_runtime.h>
#include <hip/hip_bf16.h>

typedef __hip_bfloat16 hbf16;
typedef __bf16 bf16x8 __attribute__((ext_vector_type(8)));
typedef float floatx4 __attribute__((ext_vector_type(4)));

#define N_ATOMS 4096
#define N_BONDS 8192
#define FDIM 133
#define BFDIM 147
#define HID 256
#define APM 64
#define NMOL 64

__device__ __forceinline__ float bcvt(hbf16 x) { return __bfloat162float(x); }

// ---------------- dtype detect: f32 data read as bf16 halfwords explodes ----------------
__global__ void detect_kernel(const unsigned short* __restrict__ probe, int* __restrict__ flag)
{
    const int t = threadIdx.x;
    float mx = 0.f;
    for (int i = t; i < 4096; i += 64) {
        unsigned int u = ((unsigned int)probe[i]) << 16;
        float v;
        __builtin_memcpy(&v, &u, 4);
        v = fabsf(v);
        if (!(v == v)) v = 0.f;         // drop NaN
        if (v > 1e6f) v = 1e6f;
        mx = fmaxf(mx, v);
    }
    #pragma unroll
    for (int o = 32; o > 0; o >>= 1) mx = fmaxf(mx, __shfl_xor(mx, o));
    if (t == 0) *flag = (mx > 100.f) ? 1 : 0;   // 1 = data is f32, 0 = bf16
}

__global__ void cvt_in_kernel(const void* __restrict__ src, float* __restrict__ dst, int n,
                              const int* __restrict__ flag)
{
    const int i = blockIdx.x * 256 + threadIdx.x;
    if (i >= n) return;
    if (*flag) dst[i] = ((const float*)src)[i];
    else       dst[i] = bcvt(((const hbf16*)src)[i]);
}

// ---------------- generic tiled fp32 GEMM: C = act(A @ W (+bias)) ----------------
// outmode 0: f32 row-major, 1: bf16 row-major, 2: bf16 transposed (Cb[n*N+m])
__global__ __launch_bounds__(256)
void gemm_kernel(const float* __restrict__ A, const float* __restrict__ W,
                 const float* __restrict__ bias, float* __restrict__ Cf,
                 hbf16* __restrict__ Cb, int N, int K, int Hout, int relu, int outmode)
{
    __shared__ __align__(16) float As[16][64];   // [k][m]
    __shared__ __align__(16) float Ws[16][64];   // [k][n]
    const int t = threadIdx.x;
    const int bm = blockIdx.y, bn = blockIdx.x;
    const int tm = t >> 4, tn = t & 15;
    const int ar = t >> 2, akb = (t & 3) * 4;
    const int wk = t >> 4, wc = (t & 15) * 4;
    float acc[4][4] = {};
    for (int k0 = 0; k0 < K; k0 += 16) {
        const int gm = bm * 64 + ar;
        #pragma unroll
        for (int j = 0; j < 4; j++) {
            const int gk = k0 + akb + j;
            float v = 0.f;
            if (gm < N && gk < K) v = A[(size_t)gm * K + gk];
            As[akb + j][ar] = v;
        }
        #pragma unroll
        for (int j = 0; j < 4; j++) {
            const int gk = k0 + wk, gn = bn * 64 + wc + j;
            float v = 0.f;
            if (gk < K && gn < Hout) v = W[(size_t)gk * Hout + gn];
            Ws[wk][wc + j] = v;
        }
        __syncthreads();
        #pragma unroll
        for (int kk = 0; kk < 16; kk++) {
            const float4 av = *(const float4*)&As[kk][tm * 4];
            const float4 wv = *(const float4*)&Ws[kk][tn * 4];
            const float aa[4] = {av.x, av.y, av.z, av.w};
            const float ww[4] = {wv.x, wv.y, wv.z, wv.w};
            #pragma unroll
            for (int i = 0; i < 4; i++)
                #pragma unroll
                for (int j = 0; j < 4; j++) acc[i][j] += aa[i] * ww[j];
        }
        __syncthreads();
    }
    #pragma unroll
    for (int i = 0; i < 4; i++) {
        const int mm = bm * 64 + tm * 4 + i;
        if (mm >= N) continue;
        #pragma unroll
        for (int j = 0; j < 4; j++) {
            const int nn = bn * 64 + tn * 4 + j;
            if (nn >= Hout) continue;
            float v = acc[i][j];
            if (bias) v += bias[nn];
            if (relu) v = fmaxf(v, 0.f);
            if (outmode == 0) Cf[(size_t)mm * Hout + nn] = v;
            else if (outmode == 1) Cb[(size_t)mm * Hout + nn] = __float2bfloat16(v);
            else Cb[(size_t)nn * N + mm] = __float2bfloat16(v);  // V^T for flash B-frags
        }
    }
}

// ---------------- per-molecule atom self-attention + LayerNorm ----------------
__global__ __launch_bounds__(256)
void atom_attn_kernel(const float* __restrict__ f_atoms, const float* __restrict__ qa,
                      const float* __restrict__ ka, const float* __restrict__ va,
                      const float* __restrict__ ln_g, const float* __restrict__ ln_b,
                      float* __restrict__ f_e)
{
    __shared__ float S[64][65];
    __shared__ float Y[64][136];
    const int m = blockIdx.x, t = threadIdx.x;
    const int base = m * APM;
    const float scale = 1.f / sqrtf(133.f);
    for (int e = t; e < 4096; e += 256) {
        const int a = e >> 6, b = e & 63;
        const float* qr = qa + (size_t)(base + a) * FDIM;
        const float* kr = ka + (size_t)(base + b) * FDIM;
        float s = 0.f;
        for (int k = 0; k < FDIM; k++) s += qr[k] * kr[k];
        S[a][b] = s * scale;
    }
    __syncthreads();
    const int wv = t >> 6, lnid = t & 63;
    for (int r = wv * 16; r < wv * 16 + 16; r++) {
        const float x = S[r][lnid];
        float mx = x;
        for (int o = 32; o > 0; o >>= 1) mx = fmaxf(mx, __shfl_xor(mx, o));
        const float p = __expf(x - mx);
        float sm = p;
        for (int o = 32; o > 0; o >>= 1) sm += __shfl_xor(sm, o);
        S[r][lnid] = p / sm;
    }
    __syncthreads();
    for (int e = t; e < 64 * FDIM; e += 256) {
        const int a = e / FDIM, f = e - a * FDIM;
        float acc = f_atoms[(size_t)(base + a) * FDIM + f];
        for (int b = 0; b < 64; b++)
            acc += S[a][b] * va[(size_t)(base + b) * FDIM + f];
        Y[a][f] = acc;
    }
    __syncthreads();
    for (int r = wv * 16; r < wv * 16 + 16; r++) {
        float sum = 0.f, sq = 0.f;
        for (int f = lnid; f < FDIM; f += 64) { const float v = Y[r][f]; sum += v; sq += v * v; }
        for (int o = 32; o > 0; o >>= 1) { sum += __shfl_xor(sum, o); sq += __shfl_xor(sq, o); }
        const float mu = sum / FDIM;
        const float var = sq / FDIM - mu * mu;
        const float rstd = rsqrtf(var + 1e-5f);
        for (int f = lnid; f < FDIM; f += 64) {
            const float v = (Y[r][f] - mu) * rstd;
            f_e[(size_t)(base + r) * FDIM + f] = v * ln_g[f] + ln_b[f];
        }
    }
}

// ---------------- bf16 MFMA flash attention over all 8192 bonds ----------------
__global__ __launch_bounds__(128)
void flash_kernel(const hbf16* __restrict__ Qg, const hbf16* __restrict__ Kg,
                  const hbf16* __restrict__ Vtg, float* __restrict__ Og)
{
    __shared__ __align__(16) __bf16 Qs[2][16][264];
    __shared__ __align__(16) __bf16 Ks[32][264];
    __shared__ __align__(16) __bf16 Vt[256][40];
    __shared__ __align__(16) __bf16 Ps[2][16][40];

    const int t = threadIdx.x;
    const int w = t >> 6, ln = t & 63;
    const int lane16 = ln & 15, quad = ln >> 4;
    const int rw = blockIdx.x * 32 + w * 16;

    for (int i = ln; i < 512; i += 64) {
        const int row = i >> 5, kc = (i & 31) * 8;
        *(bf16x8*)&Qs[w][row][kc] = *(const bf16x8*)&Qg[(size_t)(rw + row) * HID + kc];
    }

    floatx4 O[16];
    const floatx4 zero4 = {0.f, 0.f, 0.f, 0.f};
    #pragma unroll
    for (int i = 0; i < 16; i++) O[i] = zero4;
    float mrow[4] = {-1e30f, -1e30f, -1e30f, -1e30f};
    float lrow[4] = {0.f, 0.f, 0.f, 0.f};
    const float scale = 0.0625f;  // 1/sqrt(256)

    for (int c0 = 0; c0 < N_BONDS; c0 += 32) {
        __syncthreads();
        for (int i = t; i < 1024; i += 128) {
            const int row = i >> 5, kc = (i & 31) * 8;
            *(bf16x8*)&Ks[row][kc] = *(const bf16x8*)&Kg[(size_t)(c0 + row) * HID + kc];
        }
        for (int i = t; i < 1024; i += 128) {
            const int row = i >> 2, kc = (i & 3) * 8;
            *(bf16x8*)&Vt[row][kc] = *(const bf16x8*)&Vtg[(size_t)row * N_BONDS + c0 + kc];
        }
        __syncthreads();

        floatx4 s0 = zero4, s1 = zero4;
        #pragma unroll
        for (int ks = 0; ks < 8; ks++) {
            const bf16x8 af = *(bf16x8*)&Qs[w][lane16][ks * 32 + quad * 8];
            const bf16x8 b0 = *(bf16x8*)&Ks[lane16][ks * 32 + quad * 8];
            const bf16x8 b1 = *(bf16x8*)&Ks[16 + lane16][ks * 32 + quad * 8];
            s0 = __builtin_amdgcn_mfma_f32_16x16x32_bf16(af, b0, s0, 0, 0, 0);
            s1 = __builtin_amdgcn_mfma_f32_16x16x32_bf16(af, b1, s1, 0, 0, 0);
        }
        float alpha[4];
        #pragma unroll
        for (int r = 0; r < 4; r++) {
            const float v0 = s0[r] * scale, v1 = s1[r] * scale;
            float mx = fmaxf(v0, v1);
            #pragma unroll
            for (int o = 8; o > 0; o >>= 1) mx = fmaxf(mx, __shfl_xor(mx, o));
            const float mnew = fmaxf(mrow[r], mx);
            const float p0 = __expf(v0 - mnew), p1 = __expf(v1 - mnew);
            float ps = p0 + p1;
            #pragma unroll
            for (int o = 8; o > 0; o >>= 1) ps += __shfl_xor(ps, o);
            alpha[r] = __expf(mrow[r] - mnew);
            lrow[r] = lrow[r] * alpha[r] + ps;
            mrow[r] = mnew;
            const int row = quad * 4 + r;
            Ps[w][row][lane16] = (__bf16)p0;
            Ps[w][row][16 + lane16] = (__bf16)p1;
        }
        #pragma unroll
        for (int nt = 0; nt < 16; nt++)
            #pragma unroll
            for (int r = 0; r < 4; r++) O[nt][r] *= alpha[r];
        const bf16x8 pf = *(bf16x8*)&Ps[w][lane16][quad * 8];
        #pragma unroll
        for (int nt = 0; nt < 16; nt++) {
            const bf16x8 vf = *(bf16x8*)&Vt[nt * 16 + lane16][quad * 8];
            O[nt] = __builtin_amdgcn_mfma_f32_16x16x32_bf16(pf, vf, O[nt], 0, 0, 0);
        }
    }
    #pragma unroll
    for (int r = 0; r < 4; r++) {
        const float inv = 1.f / lrow[r];
        const int row = rw + quad * 4 + r;
        #pragma unroll
        for (int nt = 0; nt < 16; nt++)
            Og[(size_t)row * HID + nt * 16 + lane16] = O[nt][r] * inv;
    }
}

// ---------------- small fused kernels ----------------
__global__ void relu_kernel(const float* __restrict__ in, float* __restrict__ out)
{
    const size_t i = (size_t)blockIdx.x * 256 + threadIdx.x;
    out[i] = fmaxf(in[i], 0.f);
}

__global__ void gather_kernel(const float* __restrict__ msg, const int* __restrict__ a2b,
                              float* __restrict__ amsg)
{
    const int a = blockIdx.x, h = threadIdx.x;
    float s = 0.f;
    #pragma unroll
    for (int i = 0; i < 6; i++) {
        const int b = a2b[a * 6 + i];
        s += msg[(size_t)b * HID + h];
    }
    amsg[(size_t)a * HID + h] = s;
}

__global__ void pre_kernel(const float* __restrict__ amsg, const float* __restrict__ msg,
                           const int* __restrict__ b2a, const int* __restrict__ b2revb,
                           float* __restrict__ pre)
{
    const int b = blockIdx.x, h = threadIdx.x;
    pre[(size_t)b * HID + h] =
        amsg[(size_t)b2a[b] * HID + h] - msg[(size_t)b2revb[b] * HID + h];
}

__global__ __launch_bounds__(256)
void combine_kernel(const float* __restrict__ inputs, const float* __restrict__ dmpnn,
                    const float* __restrict__ att, const float* __restrict__ ww,
                    const float* __restrict__ wb, float* __restrict__ msg)
{
    const int wv = threadIdx.x >> 6, lnid = threadIdx.x & 63;
    const int row = blockIdx.x * 4 + wv;
    const float* dr = dmpnn + (size_t)row * HID;
    const float* ar = att + (size_t)row * HID;
    float dot = 0.f;
    for (int h = lnid; h < HID; h += 64)
        dot += dr[h] * ww[h] + ar[h] * ww[HID + h];
    for (int o = 32; o > 0; o >>= 1) dot += __shfl_xor(dot, o);
    const float alpha = 1.f / (1.f + __expf(-(dot + wb[0])));
    for (int h = lnid; h < HID; h += 64) {
        const float v = inputs[(size_t)row * HID + h] + alpha * dr[h] + (1.f - alpha) * ar[h];
        msg[(size_t)row * HID + h] = fmaxf(v, 0.f);
    }
}

__global__ void concat_kernel(const float* __restrict__ fe, const float* __restrict__ amsg,
                              float* __restrict__ ai)
{
    const int a = blockIdx.x, t = threadIdx.x;
    for (int f = t; f < FDIM; f += 256) ai[(size_t)a * 389 + f] = fe[(size_t)a * FDIM + f];
    for (int h = t; h < HID; h += 256) ai[(size_t)a * 389 + FDIM + h] = amsg[(size_t)a * HID + h];
}

__global__ __launch_bounds__(256)
void pool_attn_kernel(const float* __restrict__ hmWa, const float* __restrict__ atom_h,
                      float* __restrict__ att_pre)
{
    __shared__ float S[64][65];
    const int m = blockIdx.x, t = threadIdx.x;
    const int base = m * APM;
    for (int e = t; e < 4096; e += 256) {
        const int a = e >> 6, b = e & 63;
        const float* x = hmWa + (size_t)(base + a) * HID;
        const float* y = atom_h + (size_t)(base + b) * HID;
        float s = 0.f;
        for (int k = 0; k < HID; k++) s += x[k] * y[k];
        S[a][b] = s;
    }
    __syncthreads();
    const int wv = t >> 6, lnid = t & 63;
    for (int r = wv * 16; r < wv * 16 + 16; r++) {
        const float x = S[r][lnid];
        float mx = x;
        for (int o = 32; o > 0; o >>= 1) mx = fmaxf(mx, __shfl_xor(mx, o));
        const float p = __expf(x - mx);
        float sm = p;
        for (int o = 32; o > 0; o >>= 1) sm += __shfl_xor(sm, o);
        S[r][lnid] = p / sm;
    }
    __syncthreads();
    float acc[64];
    #pragma unroll
    for (int a = 0; a < 64; a++) acc[a] = 0.f;
    for (int b = 0; b < 64; b++) {
        const float v = atom_h[(size_t)(base + b) * HID + t];
        #pragma unroll
        for (int a = 0; a < 64; a++) acc[a] += S[a][b] * v;
    }
    for (int a = 0; a < 64; a++) att_pre[(size_t)(base + a) * HID + t] = acc[a];
}

__global__ void final_kernel(const float* __restrict__ atom_h, const float* __restrict__ att_wb,
                             void* __restrict__ out, const int* __restrict__ flag)
{
    const int m = blockIdx.x, h = threadIdx.x;
    float s = 0.f;
    for (int a = 0; a < APM; a++) {
        const size_t idx = (size_t)(m * APM + a) * HID + h;
        s += atom_h[idx] + att_wb[idx];
    }
    s *= (1.f / 64.f);
    if (*flag) ((float*)out)[m * HID + h] = s;
    else       ((hbf16*)out)[m * HID + h] = __float2bfloat16(s);
}

// ---------------- launch ----------------
extern "C" void kernel_launch(void* const* d_in, const int* in_sizes, int n_in,
                              void* d_out, int out_size, void* d_ws, size_t ws_size,
                              hipStream_t stream)
{
    const int* a2b    = (const int*)d_in[19];
    const int* b2a    = (const int*)d_in[20];
    const int* b2revb = (const int*)d_in[21];

    float* ws = (float*)d_ws;
    size_t off = 0;
    auto alloc = [&](size_t n) { float* p = ws + off; off += (n + 63) & ~(size_t)63; return p; };
    int* flag = (int*)alloc(64);

    // f32 copies of all float inputs (dtype-agnostic)
    const int fsizes[19] = {
        N_ATOMS * FDIM, N_BONDS * BFDIM,
        FDIM * FDIM, FDIM * FDIM, FDIM * FDIM, FDIM, FDIM,
        BFDIM * HID, HID * HID, HID * HID, HID * HID, HID * HID, HID * HID,
        2 * HID, 1, 389 * HID, HID, HID * HID, HID };
    float* fin[19];
    for (int i = 0; i < 19; i++) fin[i] = alloc((size_t)fsizes[i]);

    float* f_e    = alloc((size_t)N_ATOMS * FDIM);
    float* inputs = alloc((size_t)N_BONDS * HID);
    float* msg    = alloc((size_t)N_BONDS * HID);
    float* buf1   = alloc((size_t)N_BONDS * HID);
    float* buf2   = alloc((size_t)N_BONDS * HID);
    float* buf3   = alloc((size_t)N_BONDS * HID);
    float* buf4   = alloc((size_t)N_BONDS * HID);
    float* amsg   = alloc((size_t)N_ATOMS * HID);
    hbf16* Qb  = (hbf16*)alloc((size_t)N_BONDS * HID / 2);
    hbf16* Kb  = (hbf16*)alloc((size_t)N_BONDS * HID / 2);
    hbf16* Vtg = (hbf16*)alloc((size_t)N_BONDS * HID / 2);

    detect_kernel<<<1, 64, 0, stream>>>((const unsigned short*)d_in[1], flag);
    for (int i = 0; i < 19; i++) {
        const int n = fsizes[i];
        cvt_in_kernel<<<(n + 255) / 256, 256, 0, stream>>>(d_in[i], fin[i], n, flag);
    }
    const float *f_atoms = fin[0], *f_bonds = fin[1], *Wq_atom = fin[2], *Wk_atom = fin[3],
                *Wv_atom = fin[4], *ln_g = fin[5], *ln_b = fin[6], *Wi = fin[7], *Wh = fin[8],
                *Wq = fin[9], *Wk = fin[10], *Wv = fin[11], *Wa = fin[12], *Walpha_w = fin[13],
                *Walpha_b = fin[14], *Wo_w = fin[15], *Wo_b = fin[16], *Wb_w = fin[17],
                *Wb_b = fin[18];

    const dim3 blk(256);
    auto gemm_launch = [&](const float* A, const float* W, const float* bias, float* Cf,
                           hbf16* Cb, int N, int K, int Hout, int relu, int outmode) {
        dim3 grid((Hout + 63) / 64, (N + 63) / 64);
        gemm_kernel<<<grid, blk, 0, stream>>>(A, W, bias, Cf, Cb, N, K, Hout, relu, outmode);
    };

    // --- atom self-attention enhancement ---
    gemm_launch(f_atoms, Wq_atom, nullptr, buf1, nullptr, N_ATOMS, FDIM, FDIM, 0, 0);
    gemm_launch(f_atoms, Wk_atom, nullptr, buf2, nullptr, N_ATOMS, FDIM, FDIM, 0, 0);
    gemm_launch(f_atoms, Wv_atom, nullptr, buf3, nullptr, N_ATOMS, FDIM, FDIM, 0, 0);
    atom_attn_kernel<<<NMOL, 256, 0, stream>>>(f_atoms, buf1, buf2, buf3, ln_g, ln_b, f_e);

    // --- bond init ---
    gemm_launch(f_bonds, Wi, nullptr, inputs, nullptr, N_BONDS, BFDIM, HID, 0, 0);
    relu_kernel<<<N_BONDS, 256, 0, stream>>>(inputs, msg);

    // --- message passing ---
    for (int d = 0; d < 3; d++) {
        gather_kernel<<<N_ATOMS, 256, 0, stream>>>(msg, a2b, amsg);
        pre_kernel<<<N_BONDS, 256, 0, stream>>>(amsg, msg, b2a, b2revb, buf1);
        gemm_launch(buf1, Wh, nullptr, buf2, nullptr, N_BONDS, HID, HID, 0, 0);   // dmpnn
        gemm_launch(msg, Wq, nullptr, nullptr, Qb, N_BONDS, HID, HID, 0, 1);
        gemm_launch(msg, Wk, nullptr, nullptr, Kb, N_BONDS, HID, HID, 0, 1);
        gemm_launch(msg, Wv, nullptr, nullptr, Vtg, N_BONDS, HID, HID, 0, 2);     // V^T
        flash_kernel<<<N_BONDS / 32, 128, 0, stream>>>(Qb, Kb, Vtg, buf3);        // att_v
        gemm_launch(buf3, Wa, nullptr, buf4, nullptr, N_BONDS, HID, HID, 0, 0);   // att_msg
        combine_kernel<<<N_BONDS / 4, 256, 0, stream>>>(inputs, buf2, buf4, Walpha_w,
                                                        Walpha_b, msg);
    }

    // --- readout ---
    gather_kernel<<<N_ATOMS, 256, 0, stream>>>(msg, a2b, amsg);
    concat_kernel<<<N_ATOMS, 256, 0, stream>>>(f_e, amsg, buf1);                  // a_input
    gemm_launch(buf1, Wo_w, Wo_b, buf4, nullptr, N_ATOMS, FDIM + HID, HID, 1, 0); // atom_h

    // --- pooling ---
    gemm_launch(buf4, Wa, nullptr, buf3, nullptr, N_ATOMS, HID, HID, 0, 0);       // hmWa
    pool_attn_kernel<<<NMOL, 256, 0, stream>>>(buf3, buf4, buf1);                 // att_pre
    gemm_launch(buf1, Wb_w, Wb_b, buf2, nullptr, N_ATOMS, HID, HID, 1, 0);        // att_wb
    final_kernel<<<NMOL, 256, 0, stream>>>(buf4, buf2, d_out, flag);
}

// Round 3
// 1467.055 us; speedup vs baseline: 3.5190x; 3.5190x over previous
//
#include <hip/hip_runtime.h>
#include <hip/hip_bf16.h>

typedef __hip_bfloat16 hbf16;
typedef __bf16 bf16x8 __attribute__((ext_vector_type(8)));
typedef float floatx4 __attribute__((ext_vector_type(4)));

#define N_ATOMS 4096
#define N_BONDS 8192
#define FDIM 133
#define BFDIM 147
#define HID 256
#define APM 64
#define NMOL 64
#define FA_S 160   // padded K for f_atoms / atom weights
#define FB_S 160   // padded K for f_bonds / Wi
#define AI_S 416   // padded K for a_input / Wo_w

struct P4 { float* p[4]; };

__device__ __forceinline__ float bcvt(hbf16 x) { return __bfloat162float(x); }

// ---------------- dtype detect: f32 data read as bf16 halfwords explodes ----------------
__global__ void detect_kernel(const unsigned short* __restrict__ probe, int* __restrict__ flag)
{
    const int t = threadIdx.x;
    float mx = 0.f;
    for (int i = t; i < 4096; i += 64) {
        unsigned int u = ((unsigned int)probe[i]) << 16;
        float v;
        __builtin_memcpy(&v, &u, 4);
        v = fabsf(v);
        if (!(v == v)) v = 0.f;
        if (v > 1e6f) v = 1e6f;
        mx = fmaxf(mx, v);
    }
    #pragma unroll
    for (int o = 32; o > 0; o >>= 1) mx = fmaxf(mx, __shfl_xor(mx, o));
    if (t == 0) *flag = (mx > 100.f) ? 1 : 0;   // 1 = f32 data, 0 = bf16 data
}

__device__ __forceinline__ float load_in(const void* src, int i, int f32flag)
{
    return f32flag ? ((const float*)src)[i] : bcvt(((const hbf16*)src)[i]);
}

__global__ void cvt_in_kernel(const void* __restrict__ src, float* __restrict__ dst, int n,
                              const int* __restrict__ flag)
{
    const int i = blockIdx.x * 256 + threadIdx.x;
    if (i >= n) return;
    dst[i] = load_in(src, i, *flag);
}

// padded row copy: dst[N][Kp], zero-filled for k >= K
__global__ void cvt_pad_kernel(const void* __restrict__ src, float* __restrict__ dst,
                               int N, int K, int Kp, const int* __restrict__ flag)
{
    const int i = blockIdx.x * 256 + threadIdx.x;
    if (i >= N * Kp) return;
    const int r = i / Kp, k = i - r * Kp;
    dst[i] = (k < K) ? load_in(src, r * K + k, *flag) : 0.f;
}

// W [K][Hout] -> Wt bf16 [HoutPad][Kp], zero-padded
__global__ void wt_kernel(const void* __restrict__ src, hbf16* __restrict__ dst,
                          int K, int Hout, int Kp, int HoutPad, const int* __restrict__ flag)
{
    const int i = blockIdx.x * 256 + threadIdx.x;
    if (i >= HoutPad * Kp) return;
    const int n = i / Kp, k = i - n * Kp;
    float v = 0.f;
    if (k < K && n < Hout) v = load_in(src, k * Hout + n, *flag);
    dst[i] = __float2bfloat16(v);
}

// ---------------- bf16 MFMA GEMM, LDS-free ----------------
// C[N][Hout] = act(A @ W + bias); A f32 [N][lda] (lda = Kp), Wt bf16 [HoutPad][Kp].
// outmode 0: f32 Cf[m*ldc+n] (+ optional Cf2 = relu copy), 1: bf16 Cb[m*ldc+n],
// 2: bf16 transposed Cb[n*ldc+m] (ldc = N).
__global__ __launch_bounds__(256)
void mgemm_kernel(const float* __restrict__ A, int lda, const hbf16* __restrict__ Wt,
                  const float* __restrict__ bias, float* __restrict__ Cf,
                  float* __restrict__ Cf2, hbf16* __restrict__ Cb,
                  int N, int Hout, int ldc, int outmode, int relu)
{
    const int t = threadIdx.x, w = t >> 6, ln = t & 63;
    const int lane16 = ln & 15, quad = ln >> 4;
    const int rb = blockIdx.y * 64 + w * 16, cb = blockIdx.x * 64;
    const floatx4 zero4 = {0.f, 0.f, 0.f, 0.f};
    floatx4 acc[4] = {zero4, zero4, zero4, zero4};
    const float* ar = A + (size_t)(rb + lane16) * lda + quad * 8;
    for (int kk = 0; kk < lda; kk += 32) {
        const float4 a0 = *(const float4*)(ar + kk);
        const float4 a1 = *(const float4*)(ar + kk + 4);
        bf16x8 af;
        af[0] = (__bf16)a0.x; af[1] = (__bf16)a0.y; af[2] = (__bf16)a0.z; af[3] = (__bf16)a0.w;
        af[4] = (__bf16)a1.x; af[5] = (__bf16)a1.y; af[6] = (__bf16)a1.z; af[7] = (__bf16)a1.w;
        #pragma unroll
        for (int nt = 0; nt < 4; nt++) {
            const bf16x8 bf =
                *(const bf16x8*)&Wt[(size_t)(cb + nt * 16 + lane16) * lda + kk + quad * 8];
            acc[nt] = __builtin_amdgcn_mfma_f32_16x16x32_bf16(af, bf, acc[nt], 0, 0, 0);
        }
    }
    #pragma unroll
    for (int nt = 0; nt < 4; nt++) {
        const int n = cb + nt * 16 + lane16;
        if (n >= Hout) continue;
        const float bv = bias ? bias[n] : 0.f;
        #pragma unroll
        for (int r = 0; r < 4; r++) {
            const int m = rb + quad * 4 + r;
            float v = acc[nt][r] + bv;
            if (relu) v = fmaxf(v, 0.f);
            if (outmode == 0) {
                Cf[(size_t)m * ldc + n] = v;
                if (Cf2) Cf2[(size_t)m * ldc + n] = fmaxf(v, 0.f);
            } else if (outmode == 1) {
                Cb[(size_t)m * ldc + n] = __float2bfloat16(v);
            } else {
                Cb[(size_t)n * ldc + m] = __float2bfloat16(v);
            }
        }
    }
}

// ---------------- per-molecule atom self-attention + LayerNorm ----------------
__global__ __launch_bounds__(256)
void atom_attn_kernel(const float* __restrict__ f_atoms, const float* __restrict__ qa,
                      const float* __restrict__ ka, const float* __restrict__ va,
                      const float* __restrict__ ln_g, const float* __restrict__ ln_b,
                      float* __restrict__ f_e)
{
    __shared__ float S[64][65];
    __shared__ float Y[64][136];
    const int m = blockIdx.x, t = threadIdx.x;
    const int base = m * APM;
    const float scale = 1.f / sqrtf(133.f);
    for (int e = t; e < 4096; e += 256) {
        const int a = e >> 6, b = e & 63;
        const float* qr = qa + (size_t)(base + a) * FDIM;
        const float* kr = ka + (size_t)(base + b) * FDIM;
        float s = 0.f;
        for (int k = 0; k < FDIM; k++) s += qr[k] * kr[k];
        S[a][b] = s * scale;
    }
    __syncthreads();
    const int wv = t >> 6, lnid = t & 63;
    for (int r = wv * 16; r < wv * 16 + 16; r++) {
        const float x = S[r][lnid];
        float mx = x;
        for (int o = 32; o > 0; o >>= 1) mx = fmaxf(mx, __shfl_xor(mx, o));
        const float p = __expf(x - mx);
        float sm = p;
        for (int o = 32; o > 0; o >>= 1) sm += __shfl_xor(sm, o);
        S[r][lnid] = p / sm;
    }
    __syncthreads();
    for (int e = t; e < 64 * FDIM; e += 256) {
        const int a = e / FDIM, f = e - a * FDIM;
        float acc = f_atoms[(size_t)(base + a) * FA_S + f];
        for (int b = 0; b < 64; b++)
            acc += S[a][b] * va[(size_t)(base + b) * FDIM + f];
        Y[a][f] = acc;
    }
    __syncthreads();
    for (int r = wv * 16; r < wv * 16 + 16; r++) {
        float sum = 0.f, sq = 0.f;
        for (int f = lnid; f < FDIM; f += 64) { const float v = Y[r][f]; sum += v; sq += v * v; }
        for (int o = 32; o > 0; o >>= 1) { sum += __shfl_xor(sum, o); sq += __shfl_xor(sq, o); }
        const float mu = sum / FDIM;
        const float var = sq / FDIM - mu * mu;
        const float rstd = rsqrtf(var + 1e-5f);
        for (int f = lnid; f < FDIM; f += 64) {
            const float v = (Y[r][f] - mu) * rstd;
            f_e[(size_t)(base + r) * FDIM + f] = v * ln_g[f] + ln_b[f];
        }
    }
}

// ---------------- flash attention v2: 4-wave blocks, col-split 4, raw partials ----------------
__global__ __launch_bounds__(256)
void flash_kernel(const hbf16* __restrict__ Qg, const hbf16* __restrict__ Kg,
                  const hbf16* __restrict__ Vtg, P4 parts, float2* __restrict__ ml)
{
    __shared__ __align__(16) __bf16 Ks[32][264];
    __shared__ __align__(16) __bf16 Vt[256][40];
    __shared__ __align__(16) __bf16 Ps[4][16][40];

    const int t = threadIdx.x, w = t >> 6, ln = t & 63;
    const int lane16 = ln & 15, quad = ln >> 4;
    const int cs = blockIdx.x;
    const int rw = blockIdx.y * 64 + w * 16;
    float* __restrict__ part = parts.p[cs];

    bf16x8 qf[8];
    #pragma unroll
    for (int ks = 0; ks < 8; ks++)
        qf[ks] = *(const bf16x8*)&Qg[(size_t)(rw + lane16) * HID + ks * 32 + quad * 8];

    const floatx4 zero4 = {0.f, 0.f, 0.f, 0.f};
    floatx4 O[16];
    #pragma unroll
    for (int i = 0; i < 16; i++) O[i] = zero4;
    float mrow[4] = {-1e30f, -1e30f, -1e30f, -1e30f};
    float lrow[4] = {0.f, 0.f, 0.f, 0.f};
    const float scale = 0.0625f;  // 1/sqrt(256)

    const int cbeg = cs * 2048, cend = cbeg + 2048;
    for (int c0 = cbeg; c0 < cend; c0 += 32) {
        __syncthreads();
        #pragma unroll
        for (int ii = 0; ii < 4; ii++) {              // K tile 32x256
            const int i = t + ii * 256;
            const int row = i >> 5, kc = (i & 31) * 8;
            *(bf16x8*)&Ks[row][kc] = *(const bf16x8*)&Kg[(size_t)(c0 + row) * HID + kc];
        }
        #pragma unroll
        for (int ii = 0; ii < 4; ii++) {              // V^T tile 256x32
            const int i = t + ii * 256;
            const int row = i >> 2, kc = (i & 3) * 8;
            *(bf16x8*)&Vt[row][kc] = *(const bf16x8*)&Vtg[(size_t)row * N_BONDS + c0 + kc];
        }
        __syncthreads();

        floatx4 s0 = zero4, s1 = zero4;
        #pragma unroll
        for (int ks = 0; ks < 8; ks++) {
            const bf16x8 b0 = *(bf16x8*)&Ks[lane16][ks * 32 + quad * 8];
            const bf16x8 b1 = *(bf16x8*)&Ks[16 + lane16][ks * 32 + quad * 8];
            s0 = __builtin_amdgcn_mfma_f32_16x16x32_bf16(qf[ks], b0, s0, 0, 0, 0);
            s1 = __builtin_amdgcn_mfma_f32_16x16x32_bf16(qf[ks], b1, s1, 0, 0, 0);
        }
        float alpha[4];
        #pragma unroll
        for (int r = 0; r < 4; r++) {
            const float v0 = s0[r] * scale, v1 = s1[r] * scale;
            float mx = fmaxf(v0, v1);
            #pragma unroll
            for (int o = 8; o > 0; o >>= 1) mx = fmaxf(mx, __shfl_xor(mx, o));
            const float mnew = fmaxf(mrow[r], mx);
            const float p0 = __expf(v0 - mnew), p1 = __expf(v1 - mnew);
            float ps = p0 + p1;
            #pragma unroll
            for (int o = 8; o > 0; o >>= 1) ps += __shfl_xor(ps, o);
            alpha[r] = __expf(mrow[r] - mnew);
            lrow[r] = lrow[r] * alpha[r] + ps;
            mrow[r] = mnew;
            const int row = quad * 4 + r;
            Ps[w][row][lane16] = (__bf16)p0;
            Ps[w][row][16 + lane16] = (__bf16)p1;
        }
        #pragma unroll
        for (int nt = 0; nt < 16; nt++)
            #pragma unroll
            for (int r = 0; r < 4; r++) O[nt][r] *= alpha[r];
        const bf16x8 pf = *(bf16x8*)&Ps[w][lane16][quad * 8];
        #pragma unroll
        for (int nt = 0; nt < 16; nt++) {
            const bf16x8 vf = *(bf16x8*)&Vt[nt * 16 + lane16][quad * 8];
            O[nt] = __builtin_amdgcn_mfma_f32_16x16x32_bf16(pf, vf, O[nt], 0, 0, 0);
        }
    }
    #pragma unroll
    for (int r = 0; r < 4; r++) {
        const int row = rw + quad * 4 + r;
        #pragma unroll
        for (int nt = 0; nt < 16; nt++)
            part[(size_t)row * HID + nt * 16 + lane16] = O[nt][r];
        if (lane16 == 0) ml[cs * N_BONDS + row] = make_float2(mrow[r], lrow[r]);
    }
}

__global__ void flash_combine_kernel(P4 parts, const float2* __restrict__ ml,
                                     float* __restrict__ out)
{
    const int row = blockIdx.x, h = threadIdx.x;
    float2 e[4];
    float M = -1e30f;
    #pragma unroll
    for (int i = 0; i < 4; i++) { e[i] = ml[i * N_BONDS + row]; M = fmaxf(M, e[i].x); }
    float den = 0.f, val = 0.f;
    #pragma unroll
    for (int i = 0; i < 4; i++) {
        const float wgt = __expf(e[i].x - M);
        den += wgt * e[i].y;
        val += wgt * parts.p[i][(size_t)row * HID + h];
    }
    out[(size_t)row * HID + h] = val / den;
}

// ---------------- small fused kernels ----------------
__global__ void gather_kernel(const float* __restrict__ msg, const int* __restrict__ a2b,
                              float* __restrict__ amsg)
{
    const int a = blockIdx.x, h = threadIdx.x;
    float s = 0.f;
    #pragma unroll
    for (int i = 0; i < 6; i++) {
        const int b = a2b[a * 6 + i];
        s += msg[(size_t)b * HID + h];
    }
    amsg[(size_t)a * HID + h] = s;
}

__global__ void pre_kernel(const float* __restrict__ amsg, const float* __restrict__ msg,
                           const int* __restrict__ b2a, const int* __restrict__ b2revb,
                           float* __restrict__ pre)
{
    const int b = blockIdx.x, h = threadIdx.x;
    pre[(size_t)b * HID + h] =
        amsg[(size_t)b2a[b] * HID + h] - msg[(size_t)b2revb[b] * HID + h];
}

__global__ __launch_bounds__(256)
void combine_kernel(const float* __restrict__ inputs, const float* __restrict__ dmpnn,
                    const float* __restrict__ att, const float* __restrict__ ww,
                    const float* __restrict__ wb, float* __restrict__ msg)
{
    const int wv = threadIdx.x >> 6, lnid = threadIdx.x & 63;
    const int row = blockIdx.x * 4 + wv;
    const float* dr = dmpnn + (size_t)row * HID;
    const float* ar = att + (size_t)row * HID;
    float dot = 0.f;
    for (int h = lnid; h < HID; h += 64)
        dot += dr[h] * ww[h] + ar[h] * ww[HID + h];
    for (int o = 32; o > 0; o >>= 1) dot += __shfl_xor(dot, o);
    const float alpha = 1.f / (1.f + __expf(-(dot + wb[0])));
    for (int h = lnid; h < HID; h += 64) {
        const float v = inputs[(size_t)row * HID + h] + alpha * dr[h] + (1.f - alpha) * ar[h];
        msg[(size_t)row * HID + h] = fmaxf(v, 0.f);
    }
}

__global__ void concat_kernel(const float* __restrict__ fe, const float* __restrict__ amsg,
                              float* __restrict__ ai)
{
    const int a = blockIdx.x, t = threadIdx.x;
    for (int f = t; f < FDIM; f += 256) ai[(size_t)a * AI_S + f] = fe[(size_t)a * FDIM + f];
    for (int h = t; h < HID; h += 256) ai[(size_t)a * AI_S + FDIM + h] = amsg[(size_t)a * HID + h];
    for (int z = t; z < AI_S - FDIM - HID; z += 256) ai[(size_t)a * AI_S + FDIM + HID + z] = 0.f;
}

__global__ __launch_bounds__(256)
void pool_attn_kernel(const float* __restrict__ hmWa, const float* __restrict__ atom_h,
                      float* __restrict__ att_pre)
{
    __shared__ float S[64][65];
    const int m = blockIdx.x, t = threadIdx.x;
    const int base = m * APM;
    for (int e = t; e < 4096; e += 256) {
        const int a = e >> 6, b = e & 63;
        const float* x = hmWa + (size_t)(base + a) * HID;
        const float* y = atom_h + (size_t)(base + b) * HID;
        float s = 0.f;
        for (int k = 0; k < HID; k++) s += x[k] * y[k];
        S[a][b] = s;
    }
    __syncthreads();
    const int wv = t >> 6, lnid = t & 63;
    for (int r = wv * 16; r < wv * 16 + 16; r++) {
        const float x = S[r][lnid];
        float mx = x;
        for (int o = 32; o > 0; o >>= 1) mx = fmaxf(mx, __shfl_xor(mx, o));
        const float p = __expf(x - mx);
        float sm = p;
        for (int o = 32; o > 0; o >>= 1) sm += __shfl_xor(sm, o);
        S[r][lnid] = p / sm;
    }
    __syncthreads();
    float acc[64];
    #pragma unroll
    for (int a = 0; a < 64; a++) acc[a] = 0.f;
    for (int b = 0; b < 64; b++) {
        const float v = atom_h[(size_t)(base + b) * HID + t];
        #pragma unroll
        for (int a = 0; a < 64; a++) acc[a] += S[a][b] * v;
    }
    for (int a = 0; a < 64; a++) att_pre[(size_t)(base + a) * HID + t] = acc[a];
}

__global__ void final_kernel(const float* __restrict__ atom_h, const float* __restrict__ att_wb,
                             void* __restrict__ out, const int* __restrict__ flag)
{
    const int m = blockIdx.x, h = threadIdx.x;
    float s = 0.f;
    for (int a = 0; a < APM; a++) {
        const size_t idx = (size_t)(m * APM + a) * HID + h;
        s += atom_h[idx] + att_wb[idx];
    }
    s *= (1.f / 64.f);
    if (*flag) ((float*)out)[m * HID + h] = s;
    else       ((hbf16*)out)[m * HID + h] = __float2bfloat16(s);
}

// ---------------- launch ----------------
extern "C" void kernel_launch(void* const* d_in, const int* in_sizes, int n_in,
                              void* d_out, int out_size, void* d_ws, size_t ws_size,
                              hipStream_t stream)
{
    const int* a2b    = (const int*)d_in[19];
    const int* b2a    = (const int*)d_in[20];
    const int* b2revb = (const int*)d_in[21];

    float* ws = (float*)d_ws;
    size_t off = 0;
    auto alloc = [&](size_t n) { float* p = ws + off; off += (n + 63) & ~(size_t)63; return p; };
    int* flag = (int*)alloc(64);

    // small f32 copies
    float* ln_g     = alloc(FDIM);
    float* ln_b     = alloc(FDIM);
    float* Walpha_w = alloc(2 * HID);
    float* Walpha_b = alloc(1);
    float* Wo_b     = alloc(HID);
    float* Wb_b     = alloc(HID);
    // padded f32 activations
    float* f_atoms_p = alloc((size_t)N_ATOMS * FA_S);
    float* f_bonds_p = alloc((size_t)N_BONDS * FB_S);
    // transposed bf16 weights (alloc in float units = elems/2)
    auto balloc = [&](size_t n) { return (hbf16*)alloc((n + 1) / 2); };
    hbf16* Wt_qa = balloc((size_t)192 * FA_S);
    hbf16* Wt_ka = balloc((size_t)192 * FA_S);
    hbf16* Wt_va = balloc((size_t)192 * FA_S);
    hbf16* Wt_i  = balloc((size_t)HID * FB_S);
    hbf16* Wt_h  = balloc((size_t)HID * HID);
    hbf16* Wt_q  = balloc((size_t)HID * HID);
    hbf16* Wt_k  = balloc((size_t)HID * HID);
    hbf16* Wt_v  = balloc((size_t)HID * HID);
    hbf16* Wt_a  = balloc((size_t)HID * HID);
    hbf16* Wt_b  = balloc((size_t)HID * HID);
    hbf16* Wt_o  = balloc((size_t)HID * AI_S);

    float* f_e    = alloc((size_t)N_ATOMS * FDIM);
    float* inputs = alloc((size_t)N_BONDS * HID);
    float* msg    = alloc((size_t)N_BONDS * HID);
    float* buf1   = alloc((size_t)N_BONDS * HID);   // pre | part0 | a_input | att_pre
    float* buf2   = alloc((size_t)N_BONDS * HID);   // dmpnn | att_wb
    float* buf3   = alloc((size_t)N_BONDS * HID);   // part1 | att_v | hmWa | atom qa
    float* buf4   = alloc((size_t)N_BONDS * HID);   // part2 | att_msg | atom_h
    float* pnew   = alloc((size_t)N_BONDS * HID);   // part3 | atom ka/va reuse
    float* amsg   = alloc((size_t)N_ATOMS * HID);
    float2* ml    = (float2*)alloc((size_t)4 * N_BONDS * 2);
    hbf16* Qb  = balloc((size_t)N_BONDS * HID);
    hbf16* Kb  = balloc((size_t)N_BONDS * HID);
    hbf16* Vtg = balloc((size_t)N_BONDS * HID);

    detect_kernel<<<1, 64, 0, stream>>>((const unsigned short*)d_in[1], flag);

    auto cvt = [&](int idx, float* dst, int n) {
        cvt_in_kernel<<<(n + 255) / 256, 256, 0, stream>>>(d_in[idx], dst, n, flag);
    };
    cvt(5, ln_g, FDIM); cvt(6, ln_b, FDIM); cvt(13, Walpha_w, 2 * HID);
    cvt(14, Walpha_b, 1); cvt(16, Wo_b, HID); cvt(18, Wb_b, HID);
    cvt_pad_kernel<<<(N_ATOMS * FA_S + 255) / 256, 256, 0, stream>>>(
        d_in[0], f_atoms_p, N_ATOMS, FDIM, FA_S, flag);
    cvt_pad_kernel<<<(N_BONDS * FB_S + 255) / 256, 256, 0, stream>>>(
        d_in[1], f_bonds_p, N_BONDS, BFDIM, FB_S, flag);

    auto wt = [&](int idx, hbf16* dst, int K, int Hout, int Kp, int Hp) {
        wt_kernel<<<(Hp * Kp + 255) / 256, 256, 0, stream>>>(d_in[idx], dst, K, Hout, Kp, Hp, flag);
    };
    wt(2, Wt_qa, FDIM, FDIM, FA_S, 192);
    wt(3, Wt_ka, FDIM, FDIM, FA_S, 192);
    wt(4, Wt_va, FDIM, FDIM, FA_S, 192);
    wt(7, Wt_i, BFDIM, HID, FB_S, HID);
    wt(8, Wt_h, HID, HID, HID, HID);
    wt(9, Wt_q, HID, HID, HID, HID);
    wt(10, Wt_k, HID, HID, HID, HID);
    wt(11, Wt_v, HID, HID, HID, HID);
    wt(12, Wt_a, HID, HID, HID, HID);
    wt(17, Wt_b, HID, HID, HID, HID);
    wt(15, Wt_o, FDIM + HID, HID, AI_S, HID);

    auto mg = [&](const float* A, int lda, const hbf16* Wt, const float* bias, float* Cf,
                  float* Cf2, hbf16* Cb, int N, int Hout, int ldc, int outmode, int relu) {
        dim3 grid((Hout + 63) / 64, N / 64);
        mgemm_kernel<<<grid, 256, 0, stream>>>(A, lda, Wt, bias, Cf, Cf2, Cb,
                                               N, Hout, ldc, outmode, relu);
    };

    // --- atom self-attention enhancement ---
    mg(f_atoms_p, FA_S, Wt_qa, nullptr, buf3, nullptr, nullptr, N_ATOMS, FDIM, FDIM, 0, 0);
    mg(f_atoms_p, FA_S, Wt_ka, nullptr, buf4, nullptr, nullptr, N_ATOMS, FDIM, FDIM, 0, 0);
    mg(f_atoms_p, FA_S, Wt_va, nullptr, pnew, nullptr, nullptr, N_ATOMS, FDIM, FDIM, 0, 0);
    atom_attn_kernel<<<NMOL, 256, 0, stream>>>(f_atoms_p, buf3, buf4, pnew, ln_g, ln_b, f_e);

    // --- bond init: inputs = f_bonds@Wi, msg = relu(inputs) ---
    mg(f_bonds_p, FB_S, Wt_i, nullptr, inputs, msg, nullptr, N_BONDS, HID, HID, 0, 0);

    P4 parts; parts.p[0] = buf1; parts.p[1] = buf3; parts.p[2] = buf4; parts.p[3] = pnew;

    // --- message passing ---
    for (int d = 0; d < 3; d++) {
        gather_kernel<<<N_ATOMS, 256, 0, stream>>>(msg, a2b, amsg);
        pre_kernel<<<N_BONDS, 256, 0, stream>>>(amsg, msg, b2a, b2revb, buf1);
        mg(buf1, HID, Wt_h, nullptr, buf2, nullptr, nullptr, N_BONDS, HID, HID, 0, 0); // dmpnn
        mg(msg, HID, Wt_q, nullptr, nullptr, nullptr, Qb, N_BONDS, HID, HID, 1, 0);
        mg(msg, HID, Wt_k, nullptr, nullptr, nullptr, Kb, N_BONDS, HID, HID, 1, 0);
        mg(msg, HID, Wt_v, nullptr, nullptr, nullptr, Vtg, N_BONDS, HID, N_BONDS, 2, 0); // V^T
        flash_kernel<<<dim3(4, N_BONDS / 64), 256, 0, stream>>>(Qb, Kb, Vtg, parts, ml);
        flash_combine_kernel<<<N_BONDS, 256, 0, stream>>>(parts, ml, buf3);            // att_v
        mg(buf3, HID, Wt_a, nullptr, buf4, nullptr, nullptr, N_BONDS, HID, HID, 0, 0); // att_msg
        combine_kernel<<<N_BONDS / 4, 256, 0, stream>>>(inputs, buf2, buf4, Walpha_w,
                                                        Walpha_b, msg);
    }

    // --- readout ---
    gather_kernel<<<N_ATOMS, 256, 0, stream>>>(msg, a2b, amsg);
    concat_kernel<<<N_ATOMS, 256, 0, stream>>>(f_e, amsg, buf1);                       // a_input
    mg(buf1, AI_S, Wt_o, Wo_b, buf4, nullptr, nullptr, N_ATOMS, HID, HID, 0, 1);       // atom_h

    // --- pooling ---
    mg(buf4, HID, Wt_a, nullptr, buf3, nullptr, nullptr, N_ATOMS, HID, HID, 0, 0);     // hmWa
    pool_attn_kernel<<<NMOL, 256, 0, stream>>>(buf3, buf4, buf1);                      // att_pre
    mg(buf1, HID, Wt_b, Wb_b, buf2, nullptr, nullptr, N_ATOMS, HID, HID, 0, 1);        // att_wb
    final_kernel<<<NMOL, 256, 0, stream>>>(buf4, buf2, d_out, flag);
}

// Round 4
// 1133.975 us; speedup vs baseline: 4.5526x; 1.2937x over previous
//
#include <hip/hip_runtime.h>
#include <hip/hip_bf16.h>

typedef __hip_bfloat16 hbf16;
typedef __bf16 bf16x8 __attribute__((ext_vector_type(8)));
typedef float floatx4 __attribute__((ext_vector_type(4)));

#define N_ATOMS 4096
#define N_BONDS 8192
#define FDIM 133
#define BFDIM 147
#define HID 256
#define APM 64
#define NMOL 64
#define FA_S 160   // padded K for f_atoms / atom weights (also ldc of qa/ka)
#define FB_S 160   // padded K for f_bonds / Wi
#define AI_S 416   // padded K for a_input / Wo_w

struct P4 { float* p[4]; };
struct CvtTab { const void* src[6]; float* dst[6]; int n[6]; };
struct WTab { const void* src[11]; hbf16* dst[11]; int K[11]; int Hout[11]; int Kp[11]; int total[11]; };

__device__ __forceinline__ float bcvt(hbf16 x) { return __bfloat162float(x); }

__device__ __forceinline__ float load_in(const void* src, int i, int f32flag)
{
    return f32flag ? ((const float*)src)[i] : bcvt(((const hbf16*)src)[i]);
}

// split 8 f32 into bf16 hi + lo fragments
__device__ __forceinline__ void split8(const float4 a0, const float4 a1,
                                       bf16x8& hi, bf16x8& lo)
{
    const float v[8] = {a0.x, a0.y, a0.z, a0.w, a1.x, a1.y, a1.z, a1.w};
    #pragma unroll
    for (int i = 0; i < 8; i++) {
        const __bf16 h = (__bf16)v[i];
        hi[i] = h;
        lo[i] = (__bf16)(v[i] - (float)h);
    }
}

// ---------------- dtype detect: f32 data read as bf16 halfwords explodes ----------------
__global__ void detect_kernel(const unsigned short* __restrict__ probe, int* __restrict__ flag)
{
    const int t = threadIdx.x;
    float mx = 0.f;
    for (int i = t; i < 4096; i += 64) {
        unsigned int u = ((unsigned int)probe[i]) << 16;
        float v;
        __builtin_memcpy(&v, &u, 4);
        v = fabsf(v);
        if (!(v == v)) v = 0.f;
        if (v > 1e6f) v = 1e6f;
        mx = fmaxf(mx, v);
    }
    #pragma unroll
    for (int o = 32; o > 0; o >>= 1) mx = fmaxf(mx, __shfl_xor(mx, o));
    if (t == 0) *flag = (mx > 100.f) ? 1 : 0;   // 1 = f32 data, 0 = bf16 data
}

__global__ void small_cvt_kernel(CvtTab tab, const int* __restrict__ flag)
{
    const int f32 = *flag;
    for (int s = 0; s < 6; s++)
        for (int i = threadIdx.x; i < tab.n[s]; i += 256)
            tab.dst[s][i] = load_in(tab.src[s], i, f32);
}

// padded row copy: dst[N][Kp], zero-filled for k >= K; blockIdx.y selects segment
__global__ void cvt_pad_kernel(const void* __restrict__ src, float* __restrict__ dst,
                               int N, int K, int Kp, const int* __restrict__ flag)
{
    const int i = blockIdx.x * 256 + threadIdx.x;
    if (i >= N * Kp) return;
    const int r = i / Kp, k = i - r * Kp;
    dst[i] = (k < K) ? load_in(src, r * K + k, *flag) : 0.f;
}

// all weight transposes in one launch: W[K][Hout] -> Wt bf16 [Hp][Kp] zero-padded
__global__ void wt_all_kernel(WTab tab, const int* __restrict__ flag)
{
    const int wid = blockIdx.y;
    const int f32 = *flag;
    const int tot = tab.total[wid], Kp = tab.Kp[wid], K = tab.K[wid], Hout = tab.Hout[wid];
    hbf16* dst = tab.dst[wid];
    const void* src = tab.src[wid];
    for (int i = blockIdx.x * 256 + threadIdx.x; i < tot; i += gridDim.x * 256) {
        const int n = i / Kp, k = i - n * Kp;
        const float v = (k < K && n < Hout) ? load_in(src, k * Hout + n, f32) : 0.f;
        dst[i] = __float2bfloat16(v);
    }
}

// ---------------- bf16 MFMA GEMM, LDS-free, multi-emit ----------------
// A f32 [rows][lda], Wt bf16 [Hp][lda] (Hp >= gridDim.x*64, zero-padded).
// Emits (each optional): Cf f32 [m][ldcf], Cf2 = relu(Cf), Cbh/Cbl bf16 hi/lo [m][ldcb],
// CbT bf16 transposed [n][ldct]. Writes n < HoutStore; value zero for n >= Hout.
__global__ __launch_bounds__(256)
void mgemm_kernel(const float* __restrict__ A, int lda, const hbf16* __restrict__ Wt,
                  const float* __restrict__ bias,
                  float* __restrict__ Cf, float* __restrict__ Cf2, int ldcf,
                  hbf16* __restrict__ Cbh, hbf16* __restrict__ Cbl, int ldcb,
                  hbf16* __restrict__ CbT, int ldct,
                  int Hout, int HoutStore, int relu)
{
    const int t = threadIdx.x, w = t >> 6, ln = t & 63;
    const int lane16 = ln & 15, quad = ln >> 4;
    const int rb = blockIdx.y * 64 + w * 16, cb = blockIdx.x * 64;
    const floatx4 zero4 = {0.f, 0.f, 0.f, 0.f};
    floatx4 acc[4] = {zero4, zero4, zero4, zero4};
    const float* ar = A + (size_t)(rb + lane16) * lda + quad * 8;
    for (int kk = 0; kk < lda; kk += 32) {
        const float4 a0 = *(const float4*)(ar + kk);
        const float4 a1 = *(const float4*)(ar + kk + 4);
        bf16x8 af;
        af[0] = (__bf16)a0.x; af[1] = (__bf16)a0.y; af[2] = (__bf16)a0.z; af[3] = (__bf16)a0.w;
        af[4] = (__bf16)a1.x; af[5] = (__bf16)a1.y; af[6] = (__bf16)a1.z; af[7] = (__bf16)a1.w;
        #pragma unroll
        for (int nt = 0; nt < 4; nt++) {
            const bf16x8 bf =
                *(const bf16x8*)&Wt[(size_t)(cb + nt * 16 + lane16) * lda + kk + quad * 8];
            acc[nt] = __builtin_amdgcn_mfma_f32_16x16x32_bf16(af, bf, acc[nt], 0, 0, 0);
        }
    }
    #pragma unroll
    for (int nt = 0; nt < 4; nt++) {
        const int n = cb + nt * 16 + lane16;
        if (n >= HoutStore) continue;
        const bool valid = n < Hout;
        const float bv = (bias && valid) ? bias[n] : 0.f;
        #pragma unroll
        for (int r = 0; r < 4; r++) {
            const int m = rb + quad * 4 + r;
            float v = valid ? acc[nt][r] + bv : 0.f;
            if (relu) v = fmaxf(v, 0.f);
            if (Cf)  Cf[(size_t)m * ldcf + n] = v;
            if (Cf2) Cf2[(size_t)m * ldcf + n] = fmaxf(v, 0.f);
            if (Cbh) {
                const hbf16 h = __float2bfloat16(v);
                Cbh[(size_t)m * ldcb + n] = h;
                if (Cbl) Cbl[(size_t)m * ldcb + n] = __float2bfloat16(v - bcvt(h));
            }
            if (CbT) CbT[(size_t)n * ldct + m] = __float2bfloat16(v);
        }
    }
}

// ---------------- fused per-molecule atom attention + LayerNorm (MFMA) ----------------
// qa,ka f32 [4096][FA_S]; vT bf16 [192][4096]; f_atoms_p f32 [4096][FA_S]
__global__ __launch_bounds__(256)
void atom_fused_kernel(const float* __restrict__ qa, const float* __restrict__ ka,
                       const hbf16* __restrict__ vT, const float* __restrict__ f_atoms_p,
                       const float* __restrict__ ln_g, const float* __restrict__ ln_b,
                       float* __restrict__ f_e)
{
    __shared__ float S[64][68];
    __shared__ __bf16 P[64][72];
    __shared__ float Y[64][136];
    const int m = blockIdx.x, t = threadIdx.x;
    const int w = t >> 6, ln = t & 63;
    const int lane16 = ln & 15, quad = ln >> 4;
    const int base = m * APM;
    const floatx4 zero4 = {0.f, 0.f, 0.f, 0.f};

    // ---- S = q @ k^T (hi/lo split, 3-product) ----
    {
        floatx4 acc[4] = {zero4, zero4, zero4, zero4};
        const float* arow = qa + (size_t)(base + w * 16 + lane16) * FA_S + quad * 8;
        #pragma unroll
        for (int ks = 0; ks < 5; ks++) {
            bf16x8 ah, al;
            split8(*(const float4*)(arow + ks * 32), *(const float4*)(arow + ks * 32 + 4), ah, al);
            #pragma unroll
            for (int nt = 0; nt < 4; nt++) {
                const float* brow = ka + (size_t)(base + nt * 16 + lane16) * FA_S + ks * 32 + quad * 8;
                bf16x8 bh, bl;
                split8(*(const float4*)brow, *(const float4*)(brow + 4), bh, bl);
                acc[nt] = __builtin_amdgcn_mfma_f32_16x16x32_bf16(ah, bh, acc[nt], 0, 0, 0);
                acc[nt] = __builtin_amdgcn_mfma_f32_16x16x32_bf16(al, bh, acc[nt], 0, 0, 0);
                acc[nt] = __builtin_amdgcn_mfma_f32_16x16x32_bf16(ah, bl, acc[nt], 0, 0, 0);
            }
        }
        const float scale = 1.f / sqrtf(133.f);
        #pragma unroll
        for (int nt = 0; nt < 4; nt++)
            #pragma unroll
            for (int r = 0; r < 4; r++)
                S[w * 16 + quad * 4 + r][nt * 16 + lane16] = acc[nt][r] * scale;
    }
    // ---- softmax rows (wave-local) ----
    for (int r = w * 16; r < w * 16 + 16; r++) {
        const float x = S[r][ln];
        float mx = x;
        #pragma unroll
        for (int o = 32; o > 0; o >>= 1) mx = fmaxf(mx, __shfl_xor(mx, o));
        const float p = __expf(x - mx);
        float sm = p;
        #pragma unroll
        for (int o = 32; o > 0; o >>= 1) sm += __shfl_xor(sm, o);
        P[r][ln] = (__bf16)(p / sm);
    }
    // ---- attn_out = P @ v, residual into Y (wave-local: m-tile w) ----
    {
        floatx4 o[9];
        #pragma unroll
        for (int i = 0; i < 9; i++) o[i] = zero4;
        #pragma unroll
        for (int ks = 0; ks < 2; ks++) {
            const bf16x8 af = *(const bf16x8*)&P[w * 16 + lane16][ks * 32 + quad * 8];
            #pragma unroll
            for (int nt = 0; nt < 9; nt++) {
                const bf16x8 bfv =
                    *(const bf16x8*)&vT[(size_t)(nt * 16 + lane16) * N_ATOMS + base + ks * 32 + quad * 8];
                o[nt] = __builtin_amdgcn_mfma_f32_16x16x32_bf16(af, bfv, o[nt], 0, 0, 0);
            }
        }
        #pragma unroll
        for (int nt = 0; nt < 9; nt++) {
            const int f = nt * 16 + lane16;
            if (f >= FDIM) continue;
            #pragma unroll
            for (int r = 0; r < 4; r++) {
                const int a = w * 16 + quad * 4 + r;
                Y[a][f] = f_atoms_p[(size_t)(base + a) * FA_S + f] + o[nt][r];
            }
        }
    }
    // ---- LayerNorm rows (wave-local) ----
    for (int r = w * 16; r < w * 16 + 16; r++) {
        float sum = 0.f, sq = 0.f;
        for (int f = ln; f < FDIM; f += 64) { const float v = Y[r][f]; sum += v; sq += v * v; }
        #pragma unroll
        for (int o = 32; o > 0; o >>= 1) { sum += __shfl_xor(sum, o); sq += __shfl_xor(sq, o); }
        const float mu = sum / FDIM;
        const float var = sq / FDIM - mu * mu;
        const float rstd = rsqrtf(var + 1e-5f);
        for (int f = ln; f < FDIM; f += 64) {
            const float v = (Y[r][f] - mu) * rstd;
            f_e[(size_t)(base + r) * FDIM + f] = v * ln_g[f] + ln_b[f];
        }
    }
}

// ---------------- fused per-molecule pooling (MFMA) ----------------
// hmWa f32 [4096][256]; atom_h f32 [4096][256]; hm hi/lo bf16 [4096][256];
// hmT bf16 [256][4096]; Wtb bf16 [256][256]
__global__ __launch_bounds__(256)
void pool_fused_kernel(const float* __restrict__ hmWa, const float* __restrict__ atom_h,
                       const hbf16* __restrict__ hm_hi, const hbf16* __restrict__ hm_lo,
                       const hbf16* __restrict__ hmT, const hbf16* __restrict__ Wtb,
                       const float* __restrict__ Wb_b, void* __restrict__ out,
                       const int* __restrict__ flag)
{
    __shared__ float S[64][68];
    __shared__ __bf16 P[64][72];
    __shared__ __bf16 att[64][264];
    const int m = blockIdx.x, t = threadIdx.x;
    const int w = t >> 6, ln = t & 63;
    const int lane16 = ln & 15, quad = ln >> 4;
    const int base = m * APM;
    const floatx4 zero4 = {0.f, 0.f, 0.f, 0.f};

    // ---- S = hmWa @ hm^T (A split in reg, B hi/lo from global, 3-product) ----
    {
        floatx4 acc[4] = {zero4, zero4, zero4, zero4};
        const float* arow = hmWa + (size_t)(base + w * 16 + lane16) * HID + quad * 8;
        #pragma unroll
        for (int ks = 0; ks < 8; ks++) {
            bf16x8 ah, al;
            split8(*(const float4*)(arow + ks * 32), *(const float4*)(arow + ks * 32 + 4), ah, al);
            #pragma unroll
            for (int nt = 0; nt < 4; nt++) {
                const size_t bidx = (size_t)(base + nt * 16 + lane16) * HID + ks * 32 + quad * 8;
                const bf16x8 bh = *(const bf16x8*)&hm_hi[bidx];
                const bf16x8 bl = *(const bf16x8*)&hm_lo[bidx];
                acc[nt] = __builtin_amdgcn_mfma_f32_16x16x32_bf16(ah, bh, acc[nt], 0, 0, 0);
                acc[nt] = __builtin_amdgcn_mfma_f32_16x16x32_bf16(al, bh, acc[nt], 0, 0, 0);
                acc[nt] = __builtin_amdgcn_mfma_f32_16x16x32_bf16(ah, bl, acc[nt], 0, 0, 0);
            }
        }
        #pragma unroll
        for (int nt = 0; nt < 4; nt++)
            #pragma unroll
            for (int r = 0; r < 4; r++)
                S[w * 16 + quad * 4 + r][nt * 16 + lane16] = acc[nt][r];
    }
    // ---- softmax rows (wave-local) ----
    for (int r = w * 16; r < w * 16 + 16; r++) {
        const float x = S[r][ln];
        float mx = x;
        #pragma unroll
        for (int o = 32; o > 0; o >>= 1) mx = fmaxf(mx, __shfl_xor(mx, o));
        const float p = __expf(x - mx);
        float sm = p;
        #pragma unroll
        for (int o = 32; o > 0; o >>= 1) sm += __shfl_xor(sm, o);
        P[r][ln] = (__bf16)(p / sm);
    }
    __syncthreads();
    // ---- att_pre = P @ hm : wave w covers cols 64w..64w+63, all 64 rows ----
    {
        floatx4 o3[4][4];
        #pragma unroll
        for (int mt = 0; mt < 4; mt++)
            #pragma unroll
            for (int nt = 0; nt < 4; nt++) o3[mt][nt] = zero4;
        #pragma unroll
        for (int ks = 0; ks < 2; ks++) {
            bf16x8 af[4];
            #pragma unroll
            for (int mt = 0; mt < 4; mt++)
                af[mt] = *(const bf16x8*)&P[mt * 16 + lane16][ks * 32 + quad * 8];
            #pragma unroll
            for (int nt = 0; nt < 4; nt++) {
                const bf16x8 bfv = *(const bf16x8*)
                    &hmT[(size_t)(w * 64 + nt * 16 + lane16) * N_ATOMS + base + ks * 32 + quad * 8];
                #pragma unroll
                for (int mt = 0; mt < 4; mt++)
                    o3[mt][nt] = __builtin_amdgcn_mfma_f32_16x16x32_bf16(af[mt], bfv, o3[mt][nt], 0, 0, 0);
            }
        }
        #pragma unroll
        for (int mt = 0; mt < 4; mt++)
            #pragma unroll
            for (int nt = 0; nt < 4; nt++)
                #pragma unroll
                for (int r = 0; r < 4; r++)
                    att[mt * 16 + quad * 4 + r][w * 64 + nt * 16 + lane16] = (__bf16)o3[mt][nt][r];
    }
    __syncthreads();
    // ---- att_h = relu(att @ Wb + b); atom-sum; + hm colsum; /64 ----
    {
        floatx4 o5[4][4];
        #pragma unroll
        for (int mt = 0; mt < 4; mt++)
            #pragma unroll
            for (int nt = 0; nt < 4; nt++) o5[mt][nt] = zero4;
        #pragma unroll
        for (int ks = 0; ks < 8; ks++) {
            bf16x8 af[4];
            #pragma unroll
            for (int mt = 0; mt < 4; mt++)
                af[mt] = *(const bf16x8*)&att[mt * 16 + lane16][ks * 32 + quad * 8];
            #pragma unroll
            for (int nt = 0; nt < 4; nt++) {
                const bf16x8 bfv = *(const bf16x8*)
                    &Wtb[(size_t)(w * 64 + nt * 16 + lane16) * HID + ks * 32 + quad * 8];
                #pragma unroll
                for (int mt = 0; mt < 4; mt++)
                    o5[mt][nt] = __builtin_amdgcn_mfma_f32_16x16x32_bf16(af[mt], bfv, o5[mt][nt], 0, 0, 0);
            }
        }
        #pragma unroll
        for (int nt = 0; nt < 4; nt++) {
            const int n = w * 64 + nt * 16 + lane16;
            const float bv = Wb_b[n];
            float s = 0.f;
            #pragma unroll
            for (int mt = 0; mt < 4; mt++)
                #pragma unroll
                for (int r = 0; r < 4; r++)
                    s += fmaxf(o5[mt][nt][r] + bv, 0.f);
            s += __shfl_xor(s, 16);
            s += __shfl_xor(s, 32);
            if (quad == 0) {
                float hsum = 0.f;
                for (int a = 0; a < APM; a++)
                    hsum += atom_h[(size_t)(base + a) * HID + n];
                const float v = (s + hsum) * (1.f / 64.f);
                if (*flag) ((float*)out)[m * HID + n] = v;
                else       ((hbf16*)out)[m * HID + n] = __float2bfloat16(v);
            }
        }
    }
}

// ---------------- flash attention: 4-wave blocks, col-split 4, raw partials ----------------
__global__ __launch_bounds__(256)
void flash_kernel(const hbf16* __restrict__ Qg, const hbf16* __restrict__ Kg,
                  const hbf16* __restrict__ Vtg, P4 parts, float2* __restrict__ ml)
{
    __shared__ __align__(16) __bf16 Ks[32][264];
    __shared__ __align__(16) __bf16 Vt[256][40];
    __shared__ __align__(16) __bf16 Ps[4][16][40];

    const int t = threadIdx.x, w = t >> 6, ln = t & 63;
    const int lane16 = ln & 15, quad = ln >> 4;
    const int cs = blockIdx.x;
    const int rw = blockIdx.y * 64 + w * 16;
    float* __restrict__ part = parts.p[cs];

    bf16x8 qf[8];
    #pragma unroll
    for (int ks = 0; ks < 8; ks++)
        qf[ks] = *(const bf16x8*)&Qg[(size_t)(rw + lane16) * HID + ks * 32 + quad * 8];

    const floatx4 zero4 = {0.f, 0.f, 0.f, 0.f};
    floatx4 O[16];
    #pragma unroll
    for (int i = 0; i < 16; i++) O[i] = zero4;
    float mrow[4] = {-1e30f, -1e30f, -1e30f, -1e30f};
    float lrow[4] = {0.f, 0.f, 0.f, 0.f};
    const float scale = 0.0625f;  // 1/sqrt(256)

    const int cbeg = cs * 2048, cend = cbeg + 2048;
    for (int c0 = cbeg; c0 < cend; c0 += 32) {
        __syncthreads();
        #pragma unroll
        for (int ii = 0; ii < 4; ii++) {
            const int i = t + ii * 256;
            const int row = i >> 5, kc = (i & 31) * 8;
            *(bf16x8*)&Ks[row][kc] = *(const bf16x8*)&Kg[(size_t)(c0 + row) * HID + kc];
        }
        #pragma unroll
        for (int ii = 0; ii < 4; ii++) {
            const int i = t + ii * 256;
            const int row = i >> 2, kc = (i & 3) * 8;
            *(bf16x8*)&Vt[row][kc] = *(const bf16x8*)&Vtg[(size_t)row * N_BONDS + c0 + kc];
        }
        __syncthreads();

        floatx4 s0 = zero4, s1 = zero4;
        #pragma unroll
        for (int ks = 0; ks < 8; ks++) {
            const bf16x8 b0 = *(bf16x8*)&Ks[lane16][ks * 32 + quad * 8];
            const bf16x8 b1 = *(bf16x8*)&Ks[16 + lane16][ks * 32 + quad * 8];
            s0 = __builtin_amdgcn_mfma_f32_16x16x32_bf16(qf[ks], b0, s0, 0, 0, 0);
            s1 = __builtin_amdgcn_mfma_f32_16x16x32_bf16(qf[ks], b1, s1, 0, 0, 0);
        }
        float alpha[4];
        #pragma unroll
        for (int r = 0; r < 4; r++) {
            const float v0 = s0[r] * scale, v1 = s1[r] * scale;
            float mx = fmaxf(v0, v1);
            #pragma unroll
            for (int o = 8; o > 0; o >>= 1) mx = fmaxf(mx, __shfl_xor(mx, o));
            const float mnew = fmaxf(mrow[r], mx);
            const float p0 = __expf(v0 - mnew), p1 = __expf(v1 - mnew);
            float ps = p0 + p1;
            #pragma unroll
            for (int o = 8; o > 0; o >>= 1) ps += __shfl_xor(ps, o);
            alpha[r] = __expf(mrow[r] - mnew);
            lrow[r] = lrow[r] * alpha[r] + ps;
            mrow[r] = mnew;
            const int row = quad * 4 + r;
            Ps[w][row][lane16] = (__bf16)p0;
            Ps[w][row][16 + lane16] = (__bf16)p1;
        }
        #pragma unroll
        for (int nt = 0; nt < 16; nt++)
            #pragma unroll
            for (int r = 0; r < 4; r++) O[nt][r] *= alpha[r];
        const bf16x8 pf = *(bf16x8*)&Ps[w][lane16][quad * 8];
        #pragma unroll
        for (int nt = 0; nt < 16; nt++) {
            const bf16x8 vf = *(bf16x8*)&Vt[nt * 16 + lane16][quad * 8];
            O[nt] = __builtin_amdgcn_mfma_f32_16x16x32_bf16(pf, vf, O[nt], 0, 0, 0);
        }
    }
    #pragma unroll
    for (int r = 0; r < 4; r++) {
        const int row = rw + quad * 4 + r;
        #pragma unroll
        for (int nt = 0; nt < 16; nt++)
            part[(size_t)row * HID + nt * 16 + lane16] = O[nt][r];
        if (lane16 == 0) ml[cs * N_BONDS + row] = make_float2(mrow[r], lrow[r]);
    }
}

__global__ void flash_combine_kernel(P4 parts, const float2* __restrict__ ml,
                                     float* __restrict__ out)
{
    const int row = blockIdx.x, h = threadIdx.x;
    float2 e[4];
    float M = -1e30f;
    #pragma unroll
    for (int i = 0; i < 4; i++) { e[i] = ml[i * N_BONDS + row]; M = fmaxf(M, e[i].x); }
    float den = 0.f, val = 0.f;
    #pragma unroll
    for (int i = 0; i < 4; i++) {
        const float wgt = __expf(e[i].x - M);
        den += wgt * e[i].y;
        val += wgt * parts.p[i][(size_t)row * HID + h];
    }
    out[(size_t)row * HID + h] = val / den;
}

// ---------------- small fused kernels ----------------
__global__ void gather_kernel(const float* __restrict__ msg, const int* __restrict__ a2b,
                              float* __restrict__ amsg)
{
    const int a = blockIdx.x, h = threadIdx.x;
    float s = 0.f;
    #pragma unroll
    for (int i = 0; i < 6; i++) {
        const int b = a2b[a * 6 + i];
        s += msg[(size_t)b * HID + h];
    }
    amsg[(size_t)a * HID + h] = s;
}

__global__ void pre_kernel(const float* __restrict__ amsg, const float* __restrict__ msg,
                           const int* __restrict__ b2a, const int* __restrict__ b2revb,
                           float* __restrict__ pre)
{
    const int b = blockIdx.x, h = threadIdx.x;
    pre[(size_t)b * HID + h] =
        amsg[(size_t)b2a[b] * HID + h] - msg[(size_t)b2revb[b] * HID + h];
}

__global__ __launch_bounds__(256)
void combine_kernel(const float* __restrict__ inputs, const float* __restrict__ dmpnn,
                    const float* __restrict__ att, const float* __restrict__ ww,
                    const float* __restrict__ wb, float* __restrict__ msg)
{
    const int wv = threadIdx.x >> 6, lnid = threadIdx.x & 63;
    const int row = blockIdx.x * 4 + wv;
    const float* dr = dmpnn + (size_t)row * HID;
    const float* ar = att + (size_t)row * HID;
    float dot = 0.f;
    for (int h = lnid; h < HID; h += 64)
        dot += dr[h] * ww[h] + ar[h] * ww[HID + h];
    #pragma unroll
    for (int o = 32; o > 0; o >>= 1) dot += __shfl_xor(dot, o);
    const float alpha = 1.f / (1.f + __expf(-(dot + wb[0])));
    for (int h = lnid; h < HID; h += 64) {
        const float v = inputs[(size_t)row * HID + h] + alpha * dr[h] + (1.f - alpha) * ar[h];
        msg[(size_t)row * HID + h] = fmaxf(v, 0.f);
    }
}

__global__ void concat_kernel(const float* __restrict__ fe, const float* __restrict__ amsg,
                              float* __restrict__ ai)
{
    const int a = blockIdx.x, t = threadIdx.x;
    for (int f = t; f < FDIM; f += 256) ai[(size_t)a * AI_S + f] = fe[(size_t)a * FDIM + f];
    for (int h = t; h < HID; h += 256) ai[(size_t)a * AI_S + FDIM + h] = amsg[(size_t)a * HID + h];
    for (int z = t; z < AI_S - FDIM - HID; z += 256) ai[(size_t)a * AI_S + FDIM + HID + z] = 0.f;
}

// ---------------- launch ----------------
extern "C" void kernel_launch(void* const* d_in, const int* in_sizes, int n_in,
                              void* d_out, int out_size, void* d_ws, size_t ws_size,
                              hipStream_t stream)
{
    const int* a2b    = (const int*)d_in[19];
    const int* b2a    = (const int*)d_in[20];
    const int* b2revb = (const int*)d_in[21];

    float* ws = (float*)d_ws;
    size_t off = 0;
    auto alloc = [&](size_t n) { float* p = ws + off; off += (n + 63) & ~(size_t)63; return p; };
    int* flag = (int*)alloc(64);

    float* ln_g     = alloc(FDIM);
    float* ln_b     = alloc(FDIM);
    float* Walpha_w = alloc(2 * HID);
    float* Walpha_b = alloc(64);
    float* Wo_b     = alloc(HID);
    float* Wb_b     = alloc(HID);
    float* f_atoms_p = alloc((size_t)N_ATOMS * FA_S);
    float* f_bonds_p = alloc((size_t)N_BONDS * FB_S);
    auto balloc = [&](size_t n) { return (hbf16*)alloc((n + 1) / 2); };
    hbf16* Wt_qa = balloc((size_t)192 * FA_S);
    hbf16* Wt_ka = balloc((size_t)192 * FA_S);
    hbf16* Wt_va = balloc((size_t)192 * FA_S);
    hbf16* Wt_i  = balloc((size_t)HID * FB_S);
    hbf16* Wt_h  = balloc((size_t)HID * HID);
    hbf16* Wt_q  = balloc((size_t)HID * HID);
    hbf16* Wt_k  = balloc((size_t)HID * HID);
    hbf16* Wt_v  = balloc((size_t)HID * HID);
    hbf16* Wt_a  = balloc((size_t)HID * HID);
    hbf16* Wt_b  = balloc((size_t)HID * HID);
    hbf16* Wt_o  = balloc((size_t)HID * AI_S);

    float* f_e    = alloc((size_t)N_ATOMS * FDIM);
    float* inputs = alloc((size_t)N_BONDS * HID);
    float* msg    = alloc((size_t)N_BONDS * HID);
    float* buf1   = alloc((size_t)N_BONDS * HID);   // qa | pre | part0 | a_input
    float* buf2   = alloc((size_t)N_BONDS * HID);   // ka | dmpnn
    float* buf3   = alloc((size_t)N_BONDS * HID);   // vT | part1 | att_v | hmWa
    float* buf4   = alloc((size_t)N_BONDS * HID);   // part2 | att_msg | atom_h
    float* pnew   = alloc((size_t)N_BONDS * HID);   // part3
    float* amsg   = alloc((size_t)N_ATOMS * HID);
    float2* ml    = (float2*)alloc((size_t)4 * N_BONDS * 2);
    hbf16* Qb  = balloc((size_t)N_BONDS * HID);     // later: hm_hi
    hbf16* Kb  = balloc((size_t)N_BONDS * HID);     // later: hm_lo
    hbf16* Vtg = balloc((size_t)N_BONDS * HID);     // later: hmT
    hbf16* vTa = (hbf16*)buf3;                       // atom V^T [192][4096]

    detect_kernel<<<1, 64, 0, stream>>>((const unsigned short*)d_in[1], flag);

    CvtTab ct;
    ct.src[0] = d_in[5];  ct.dst[0] = ln_g;     ct.n[0] = FDIM;
    ct.src[1] = d_in[6];  ct.dst[1] = ln_b;     ct.n[1] = FDIM;
    ct.src[2] = d_in[13]; ct.dst[2] = Walpha_w; ct.n[2] = 2 * HID;
    ct.src[3] = d_in[14]; ct.dst[3] = Walpha_b; ct.n[3] = 1;
    ct.src[4] = d_in[16]; ct.dst[4] = Wo_b;     ct.n[4] = HID;
    ct.src[5] = d_in[18]; ct.dst[5] = Wb_b;     ct.n[5] = HID;
    small_cvt_kernel<<<1, 256, 0, stream>>>(ct, flag);

    cvt_pad_kernel<<<(N_ATOMS * FA_S + 255) / 256, 256, 0, stream>>>(
        d_in[0], f_atoms_p, N_ATOMS, FDIM, FA_S, flag);
    cvt_pad_kernel<<<(N_BONDS * FB_S + 255) / 256, 256, 0, stream>>>(
        d_in[1], f_bonds_p, N_BONDS, BFDIM, FB_S, flag);

    WTab wt;
    const void* wsrc[11] = {d_in[2], d_in[3], d_in[4], d_in[7], d_in[8], d_in[9],
                            d_in[10], d_in[11], d_in[12], d_in[17], d_in[15]};
    hbf16* wdst[11] = {Wt_qa, Wt_ka, Wt_va, Wt_i, Wt_h, Wt_q, Wt_k, Wt_v, Wt_a, Wt_b, Wt_o};
    const int wK[11]  = {FDIM, FDIM, FDIM, BFDIM, HID, HID, HID, HID, HID, HID, FDIM + HID};
    const int wH[11]  = {FDIM, FDIM, FDIM, HID, HID, HID, HID, HID, HID, HID, HID};
    const int wKp[11] = {FA_S, FA_S, FA_S, FB_S, HID, HID, HID, HID, HID, HID, AI_S};
    const int wHp[11] = {192, 192, 192, HID, HID, HID, HID, HID, HID, HID, HID};
    for (int i = 0; i < 11; i++) {
        wt.src[i] = wsrc[i]; wt.dst[i] = wdst[i]; wt.K[i] = wK[i]; wt.Hout[i] = wH[i];
        wt.Kp[i] = wKp[i]; wt.total[i] = wHp[i] * wKp[i];
    }
    wt_all_kernel<<<dim3(416, 11), 256, 0, stream>>>(wt, flag);

    auto mg = [&](const float* A, int lda, const hbf16* Wt, const float* bias,
                  float* Cf, float* Cf2, int ldcf, hbf16* Cbh, hbf16* Cbl, int ldcb,
                  hbf16* CbT, int ldct, int rows, int Hout, int HoutStore, int relu) {
        dim3 grid((HoutStore + 63) / 64, rows / 64);
        mgemm_kernel<<<grid, 256, 0, stream>>>(A, lda, Wt, bias, Cf, Cf2, ldcf,
                                               Cbh, Cbl, ldcb, CbT, ldct,
                                               Hout, HoutStore, relu);
    };

    // --- atom self-attention stage ---
    mg(f_atoms_p, FA_S, Wt_qa, nullptr, buf1, nullptr, FA_S, nullptr, nullptr, 0,
       nullptr, 0, N_ATOMS, FDIM, FA_S, 0);                                     // qa
    mg(f_atoms_p, FA_S, Wt_ka, nullptr, buf2, nullptr, FA_S, nullptr, nullptr, 0,
       nullptr, 0, N_ATOMS, FDIM, FA_S, 0);                                     // ka
    mg(f_atoms_p, FA_S, Wt_va, nullptr, nullptr, nullptr, 0, nullptr, nullptr, 0,
       vTa, N_ATOMS, N_ATOMS, FDIM, 192, 0);                                    // vT (zero-padded)
    atom_fused_kernel<<<NMOL, 256, 0, stream>>>(buf1, buf2, vTa, f_atoms_p, ln_g, ln_b, f_e);

    // --- bond init: inputs = f_bonds@Wi, msg = relu(inputs) ---
    mg(f_bonds_p, FB_S, Wt_i, nullptr, inputs, msg, HID, nullptr, nullptr, 0,
       nullptr, 0, N_BONDS, HID, HID, 0);

    P4 parts; parts.p[0] = buf1; parts.p[1] = buf3; parts.p[2] = buf4; parts.p[3] = pnew;

    // --- message passing ---
    for (int d = 0; d < 3; d++) {
        gather_kernel<<<N_ATOMS, 256, 0, stream>>>(msg, a2b, amsg);
        pre_kernel<<<N_BONDS, 256, 0, stream>>>(amsg, msg, b2a, b2revb, buf1);
        mg(buf1, HID, Wt_h, nullptr, buf2, nullptr, HID, nullptr, nullptr, 0,
           nullptr, 0, N_BONDS, HID, HID, 0);                                   // dmpnn
        mg(msg, HID, Wt_q, nullptr, nullptr, nullptr, 0, Qb, nullptr, HID,
           nullptr, 0, N_BONDS, HID, HID, 0);
        mg(msg, HID, Wt_k, nullptr, nullptr, nullptr, 0, Kb, nullptr, HID,
           nullptr, 0, N_BONDS, HID, HID, 0);
        mg(msg, HID, Wt_v, nullptr, nullptr, nullptr, 0, nullptr, nullptr, 0,
           Vtg, N_BONDS, N_BONDS, HID, HID, 0);                                 // V^T
        flash_kernel<<<dim3(4, N_BONDS / 64), 256, 0, stream>>>(Qb, Kb, Vtg, parts, ml);
        flash_combine_kernel<<<N_BONDS, 256, 0, stream>>>(parts, ml, buf3);     // att_v
        mg(buf3, HID, Wt_a, nullptr, buf4, nullptr, HID, nullptr, nullptr, 0,
           nullptr, 0, N_BONDS, HID, HID, 0);                                   // att_msg
        combine_kernel<<<N_BONDS / 4, 256, 0, stream>>>(inputs, buf2, buf4, Walpha_w,
                                                        Walpha_b, msg);
    }

    // --- readout ---
    gather_kernel<<<N_ATOMS, 256, 0, stream>>>(msg, a2b, amsg);
    concat_kernel<<<N_ATOMS, 256, 0, stream>>>(f_e, amsg, buf1);                // a_input
    // atom_h: f32 + bf16 hi/lo rows + bf16 transposed (into dead Qb/Kb/Vtg)
    mg(buf1, AI_S, Wt_o, Wo_b, buf4, nullptr, HID, Qb, Kb, HID,
       Vtg, N_ATOMS, N_ATOMS, HID, HID, 1);

    // --- pooling ---
    mg(buf4, HID, Wt_a, nullptr, buf3, nullptr, HID, nullptr, nullptr, 0,
       nullptr, 0, N_ATOMS, HID, HID, 0);                                       // hmWa
    pool_fused_kernel<<<NMOL, 256, 0, stream>>>(buf3, buf4, Qb, Kb, Vtg, Wt_b,
                                                Wb_b, d_out, flag);
}